// Round 15
// baseline (962.058 us; speedup 1.0000x reference)
//
#include <hip/hip_runtime.h>

// Sparse voxel downsample (FACTOR=2, RES=256 -> res=128, B=2, C=64).
// code = ((b*128 + x/2)*128 + y/2)*128 + z/2  in [0, 4194304)
// u8 dense histogram; ONE decoupled-lookback scan kernel (replaces
// block_sums + scan_totals + scan_write) produces sorted rank, row_start,
// uniq_cc, wprefix; counting-sort indices; then the validated gather16 hot
// pass: random 256B reads (L3-warm feats), sequential NT writes, depth-4
// MLP, in-register mean, no feature atomics.

#define RES2 128
#define NCODES (2 * 128 * 128 * 128)   // 4194304 codes
#define NW (NCODES / 4)                // 1048576 u32 words in u8 histogram
#define SBLK 1024                      // scan blocks (1024 words each)

typedef unsigned long long u64;
typedef float f4 __attribute__((ext_vector_type(4)));

__device__ __forceinline__ u64 pack_word(unsigned w) {
    unsigned b0 = w & 0xFFu, b1 = (w >> 8) & 0xFFu,
             b2 = (w >> 16) & 0xFFu, b3 = w >> 24;
    return ((u64)(b0 + b1 + b2 + b3) << 32) |
           (u64)((b0 != 0) + (b1 != 0) + (b2 != 0) + (b3 != 0));
}

// Zero cnt8 (4.19 MB) + lookback state. Runtime fill kernel is 53 GB/s; ours
// streams at full rate.
__global__ void zero_cnt(uint4* __restrict__ p, unsigned* __restrict__ flag) {
    int i = blockIdx.x * 256 + threadIdx.x;   // 1024*256 = NW/4
    p[i] = make_uint4(0u, 0u, 0u, 0u);
    if (i < SBLK) flag[i] = 0u;
}

__global__ void count_codes(const int* __restrict__ coords,
                            unsigned* __restrict__ cnt8,
                            int* __restrict__ codes, int n) {
    int i = blockIdx.x * 256 + threadIdx.x;
    if (i >= n) return;
    const int4 v = reinterpret_cast<const int4*>(coords)[i];
    int code = (((v.x * RES2 + (v.y >> 1)) * RES2 + (v.z >> 1)) * RES2) + (v.w >> 1);
    codes[i] = code;
    atomicAdd(&cnt8[code >> 2], 1u << (8 * (code & 3)));   // u8 lanes, max ~9
}

// Fused scan with decoupled lookback. Block b owns words [b*1024, b*1024+1024)
// (as 256 uint4). Status: 0=invalid, 1=aggregate ready, 2=prefix ready.
__global__ void scan_fused(const unsigned* __restrict__ cnt8,
                           unsigned* __restrict__ flag,
                           u64* __restrict__ valA,
                           u64* __restrict__ valP,
                           unsigned* __restrict__ nuq,
                           unsigned* __restrict__ wprefix,
                           unsigned* __restrict__ uniq_cc,
                           unsigned* __restrict__ row_end) {
    __shared__ u64 sh[256];
    __shared__ u64 shbase;
    const int t = threadIdx.x;
    const int b = blockIdx.x;
    const int w4i = b * 256 + t;

    const uint4 w = reinterpret_cast<const uint4*>(cnt8)[w4i];
    unsigned ws[4] = {w.x, w.y, w.z, w.w};
    u64 pw[4], tot = 0;
#pragma unroll
    for (int j = 0; j < 4; ++j) { pw[j] = pack_word(ws[j]); tot += pw[j]; }
    sh[t] = tot;
    __syncthreads();
    for (int off = 1; off < 256; off <<= 1) {
        u64 add = (t >= off) ? sh[t - off] : 0ull;
        __syncthreads();
        sh[t] += add;
        __syncthreads();
    }
    // sh[t] = inclusive scan of per-thread tots; sh[255] = block aggregate.

    if (t == 255) {
        atomicExch(&valA[b], sh[255]);
        __threadfence();
        atomicExch(&flag[b], 1u);
    }
    if (t == 0) {
        u64 run = 0;
        for (int j = b - 1; j >= 0; ) {
            unsigned f;
            do { f = atomicAdd(&flag[j], 0u); } while (f == 0u);
            __threadfence();
            if (f == 2u) { run += atomicAdd(&valP[j], 0ull); break; }
            run += atomicAdd(&valA[j], 0ull);
            --j;
        }
        shbase = run;
        u64 inc = run + sh[255];
        atomicExch(&valP[b], inc);
        __threadfence();
        atomicExch(&flag[b], 2u);
        if (b == SBLK - 1) *nuq = (unsigned)(inc & 0xFFFFFFFFull);
    }
    __syncthreads();

    u64 run = shbase + ((t == 0) ? 0ull : sh[t - 1]);
    uint4 wp;
#pragma unroll
    for (int j = 0; j < 4; ++j) {
        unsigned flagbase = (unsigned)(run & 0xFFFFFFFFull);
        unsigned stbase = (unsigned)(run >> 32);
        ((unsigned*)&wp)[j] = flagbase;
        int code0 = (w4i * 4 + j) * 4;
        unsigned occ = 0, csum = 0;
#pragma unroll
        for (int jj = 0; jj < 4; ++jj) {
            unsigned cnt = (ws[j] >> (8 * jj)) & 0xFFu;
            if (cnt) {
                unsigned r = flagbase + occ;
                uniq_cc[r] = (unsigned)(code0 + jj) | (cnt << 22);
                row_end[r] = stbase + csum;
            }
            occ += (cnt != 0);
            csum += cnt;
        }
        run += pw[j];
    }
    reinterpret_cast<uint4*>(wprefix)[w4i] = wp;
}

// Counting sort of indices by rank (rank recomputed from cnt8 + wprefix).
// After this, row_end[r] = start+cnt.
__global__ void fill_sorted(const int* __restrict__ codes,
                            const unsigned* __restrict__ cnt8,
                            const unsigned* __restrict__ wprefix,
                            unsigned* __restrict__ row_end,
                            int* __restrict__ sorted_idx, int n) {
    int i = blockIdx.x * 256 + threadIdx.x;
    if (i >= n) return;
    int c = codes[i];
    unsigned w = cnt8[c >> 2];
    unsigned base = wprefix[c >> 2];
    int j = c & 3;
    unsigned occ = 0;
    if (j > 0) occ += ((w & 0xFFu) != 0);
    if (j > 1) occ += (((w >> 8) & 0xFFu) != 0);
    if (j > 2) occ += (((w >> 16) & 0xFFu) != 0);
    unsigned r = base + occ;
    unsigned pos = atomicAdd(&row_end[r], 1u);
    sorted_idx[pos] = i;
}

// Hot pass: 16 output rows per wave (quarter-wave = one 256B row, 4 batches
// = measured-optimal MLP depth). Regular loads (L3-warm feats), NT stores.
__global__ void gather16(const f4* __restrict__ feats4,
                         const int* __restrict__ sorted_idx,
                         const unsigned* __restrict__ row_end,
                         const unsigned* __restrict__ uniq_cc,
                         const unsigned* __restrict__ nuq_p,
                         f4* __restrict__ outF4,
                         f4* __restrict__ outC4, int n) {
    int tid = blockIdx.x * 256 + threadIdx.x;
    int wave = tid >> 6;
    int lane = threadIdx.x & 63;
    int q = lane >> 4;
    int sub = lane & 15;
    int rb = wave * 16 + q;
    int nuq = (int)*nuq_p;

    if (rb + 12 < nuq) {   // fast path: all 4 rows valid
        int r[4];
        unsigned en[4], cc[4];
#pragma unroll
        for (int k = 0; k < 4; ++k) r[k] = rb + k * 4;
#pragma unroll
        for (int k = 0; k < 4; ++k) en[k] = row_end[r[k]];
#pragma unroll
        for (int k = 0; k < 4; ++k) cc[k] = uniq_cc[r[k]];
        int cnt[4], st[4], i0[4];
#pragma unroll
        for (int k = 0; k < 4; ++k) {
            cnt[k] = (int)(cc[k] >> 22);
            st[k] = (int)en[k] - cnt[k];
        }
#pragma unroll
        for (int k = 0; k < 4; ++k) i0[k] = sorted_idx[st[k]];
        f4 a[4];
#pragma unroll
        for (int k = 0; k < 4; ++k)
            a[k] = feats4[(size_t)i0[k] * 16 + sub];
#pragma unroll
        for (int k = 0; k < 4; ++k) {
            if (cnt[k] > 1) {
                for (int m = 1; m < cnt[k]; ++m) {
                    int i = sorted_idx[st[k] + m];
                    a[k] += feats4[(size_t)i * 16 + sub];
                }
                a[k] *= (1.0f / (float)cnt[k]);
            }
            __builtin_nontemporal_store(a[k], &outF4[(size_t)r[k] * 16 + sub]);
            if (sub == 0) {
                unsigned code = cc[k] & 0x3FFFFFu;
                f4 cv = {(float)(code >> 21), (float)((code >> 14) & 127),
                         (float)((code >> 7) & 127), (float)(code & 127)};
                __builtin_nontemporal_store(cv, &outC4[r[k]]);
            }
        }
    } else {
#pragma unroll
        for (int k = 0; k < 4; ++k) {
            int r = rb + k * 4;
            if (r >= n) continue;
            if (r < nuq) {
                unsigned en = row_end[r];
                unsigned cc = uniq_cc[r];
                int cnt = (int)(cc >> 22);
                int st = (int)en - cnt;
                f4 a = {0.f, 0.f, 0.f, 0.f};
                for (int m = 0; m < cnt; ++m) {
                    int i = sorted_idx[st + m];
                    a += feats4[(size_t)i * 16 + sub];
                }
                a *= (1.0f / (float)cnt);
                outF4[(size_t)r * 16 + sub] = a;
                if (sub == 0) {
                    unsigned code = cc & 0x3FFFFFu;
                    f4 cv = {(float)(code >> 21), (float)((code >> 14) & 127),
                             (float)((code >> 7) & 127), (float)(code & 127)};
                    outC4[r] = cv;
                }
            } else {
                f4 zz = {0.f, 0.f, 0.f, 0.f};
                outF4[(size_t)r * 16 + sub] = zz;
                if (sub == 0) {
                    f4 mm = {-1.f, -1.f, -1.f, -1.f};
                    outC4[r] = mm;
                }
            }
        }
    }
}

extern "C" void kernel_launch(void* const* d_in, const int* in_sizes, int n_in,
                              void* d_out, int out_size, void* d_ws, size_t ws_size,
                              hipStream_t stream) {
    const float* feats = (const float*)d_in[0];
    const int* coords = (const int*)d_in[1];
    const int n = in_sizes[1] / 4;   // N = 500000

    float* outF = (float*)d_out;
    f4* outC4 = (f4*)(outF + (size_t)n * 64);

    unsigned* cnt8 = (unsigned*)d_ws;              // NW u32 (4.19 MB), 16-al
    unsigned* wprefix = cnt8 + NW;                 // NW u32 (4.19 MB), 16-al
    u64* valA = (u64*)(wprefix + NW);              // SBLK u64
    u64* valP = valA + SBLK;                       // SBLK u64
    unsigned* flag = (unsigned*)(valP + SBLK);     // SBLK u32
    unsigned* nuq = flag + SBLK;                   // 1 (+3 pad)
    int* codes = (int*)(nuq + 4);                  // n
    unsigned* uniq_cc = (unsigned*)(codes + n);    // n
    unsigned* row_end = uniq_cc + n;               // n
    int* sorted_idx = (int*)(row_end + n);         // n

    zero_cnt<<<1024, 256, 0, stream>>>((uint4*)cnt8, flag);
    count_codes<<<(n + 255) / 256, 256, 0, stream>>>(coords, cnt8, codes, n);
    scan_fused<<<SBLK, 256, 0, stream>>>(cnt8, flag, valA, valP, nuq,
                                         wprefix, uniq_cc, row_end);
    fill_sorted<<<(n + 255) / 256, 256, 0, stream>>>(codes, cnt8, wprefix,
                                                     row_end, sorted_idx, n);

    int waves = (n + 15) / 16;
    int blocks = (waves * 64 + 255) / 256;
    gather16<<<blocks, 256, 0, stream>>>((const f4*)feats, sorted_idx,
                                         row_end, uniq_cc, nuq,
                                         (f4*)outF, outC4, n);
}

// Round 16
// 123.041 us; speedup vs baseline: 7.8190x; 7.8190x over previous
//
#include <hip/hip_runtime.h>

// Sparse voxel downsample (FACTOR=2, RES=256 -> res=128, B=2, C=64).
// code = ((b*128 + x/2)*128 + y/2)*128 + z/2  in [0, 4194304)
// u8 dense histogram + 2-level packed (flag,count) scan -> sorted rank AND
// row_start per unique code (== jnp.unique order). Rank re-derived from
// per-word occupied-prefix (wprefix). Counting-sort the INDICES by rank,
// then a gather hot pass (depth 4, regular loads AND stores -- L2/L3 buffer
// both streams; NT variants measured slower): in-register mean, no atomics.

#define RES2 128
#define NCODES (2 * 128 * 128 * 128)   // 4194304 codes
#define NW (NCODES / 4)                // u32 words in u8 histogram
#define HBLK 4096                      // blocks over code space (1024 codes)

typedef unsigned long long u64;
typedef float f4 __attribute__((ext_vector_type(4)));

// Zero cnt8 (4.19 MB) with uint4 stores (runtime fill kernel runs at 53 GB/s).
__global__ void zero_cnt(uint4* __restrict__ p) {
    int i = blockIdx.x * 256 + threadIdx.x;   // 1024*256 = 262144 = NW/4
    p[i] = make_uint4(0u, 0u, 0u, 0u);
}

__global__ void count_codes(const int* __restrict__ coords,
                            unsigned* __restrict__ cnt8,
                            int* __restrict__ codes, int n) {
    int i = blockIdx.x * 256 + threadIdx.x;
    if (i >= n) return;
    const int4 v = reinterpret_cast<const int4*>(coords)[i];
    int code = (((v.x * RES2 + (v.y >> 1)) * RES2 + (v.z >> 1)) * RES2) + (v.w >> 1);
    codes[i] = code;
    atomicAdd(&cnt8[code >> 2], 1u << (8 * (code & 3)));   // u8 lanes, max ~9
}

// Per block of 1024 codes: packed (count_sum<<32 | flag_sum).
__global__ void block_sums(const unsigned* __restrict__ cnt8,
                           u64* __restrict__ btot) {
    __shared__ u64 sh[256];
    int t = threadIdx.x;
    unsigned w = cnt8[blockIdx.x * 256 + t];
    unsigned c0 = w & 0xFFu, c1 = (w >> 8) & 0xFFu,
             c2 = (w >> 16) & 0xFFu, c3 = w >> 24;
    u64 s = ((u64)(c0 + c1 + c2 + c3) << 32) |
            (u64)((c0 != 0) + (c1 != 0) + (c2 != 0) + (c3 != 0));
    sh[t] = s;
    __syncthreads();
    for (int off = 128; off > 0; off >>= 1) {
        if (t < off) sh[t] += sh[t + off];
        __syncthreads();
    }
    if (t == 0) btot[blockIdx.x] = sh[0];
}

// Single block: exclusive scan over 4096 packed totals; n_unique -> *nuq.
__global__ void scan_totals(u64* __restrict__ btot, unsigned* __restrict__ nuq) {
    __shared__ u64 sh[1024];
    int t = threadIdx.x;
    int base = t * 4;
    u64 v[4], e[4], s = 0;
#pragma unroll
    for (int j = 0; j < 4; ++j) { v[j] = btot[base + j]; e[j] = s; s += v[j]; }
    sh[t] = s;
    __syncthreads();
    for (int off = 1; off < 1024; off <<= 1) {
        u64 add = (t >= off) ? sh[t - off] : 0ull;
        __syncthreads();
        sh[t] += add;
        __syncthreads();
    }
    u64 excl = (t == 0) ? 0ull : sh[t - 1];
#pragma unroll
    for (int j = 0; j < 4; ++j) btot[base + j] = excl + e[j];
    if (t == 1023) *nuq = (unsigned)(sh[1023] & 0xFFFFFFFFull);
}

// Second pass: per-block packed scan + base. wprefix[word] = flag prefix
// (sequential write); per occupied code (r monotone -> near-sequential):
// uniq_cc[r] = code | cnt<<22;  row_end[r] = row_start.
__global__ void scan_write(const unsigned* __restrict__ cnt8,
                           const u64* __restrict__ btot,
                           unsigned* __restrict__ wprefix,
                           unsigned* __restrict__ uniq_cc,
                           unsigned* __restrict__ row_end) {
    __shared__ u64 sh[256];
    int t = threadIdx.x;
    int widx = blockIdx.x * 256 + t;
    unsigned w = cnt8[widx];
    unsigned c4[4] = {w & 0xFFu, (w >> 8) & 0xFFu, (w >> 16) & 0xFFu, w >> 24};
    u64 e[4], s = 0;
#pragma unroll
    for (int j = 0; j < 4; ++j) {
        e[j] = s;
        s += ((u64)c4[j] << 32) | (u64)(c4[j] != 0);
    }
    sh[t] = s;
    __syncthreads();
    for (int off = 1; off < 256; off <<= 1) {
        u64 add = (t >= off) ? sh[t - off] : 0ull;
        __syncthreads();
        sh[t] += add;
        __syncthreads();
    }
    u64 texcl = ((t == 0) ? 0ull : sh[t - 1]) + btot[blockIdx.x];
    wprefix[widx] = (unsigned)(texcl & 0xFFFFFFFFull);
    int cbase = widx * 4;
#pragma unroll
    for (int j = 0; j < 4; ++j) {
        if (c4[j]) {
            unsigned r = (unsigned)((texcl + e[j]) & 0xFFFFFFFFull);
            unsigned st = (unsigned)((texcl + e[j]) >> 32);
            int code = cbase + j;
            uniq_cc[r] = (unsigned)code | (c4[j] << 22);
            row_end[r] = st;
        }
    }
}

// Counting sort of indices by rank (rank recomputed from cnt8 + wprefix).
// After this, row_end[r] = start+cnt.
__global__ void fill_sorted(const int* __restrict__ codes,
                            const unsigned* __restrict__ cnt8,
                            const unsigned* __restrict__ wprefix,
                            unsigned* __restrict__ row_end,
                            int* __restrict__ sorted_idx, int n) {
    int i = blockIdx.x * 256 + threadIdx.x;
    if (i >= n) return;
    int c = codes[i];
    unsigned w = cnt8[c >> 2];
    unsigned base = wprefix[c >> 2];
    int j = c & 3;
    unsigned occ = 0;
    if (j > 0) occ += ((w & 0xFFu) != 0);
    if (j > 1) occ += (((w >> 8) & 0xFFu) != 0);
    if (j > 2) occ += (((w >> 16) & 0xFFu) != 0);
    unsigned r = base + occ;
    unsigned pos = atomicAdd(&row_end[r], 1u);
    sorted_idx[pos] = i;
}

// Hot pass: 16 output rows per wave (quarter-wave = one 256B row, 4 batches
// = measured-optimal MLP depth). Regular loads and stores throughout.
__global__ void gather16(const f4* __restrict__ feats4,
                         const int* __restrict__ sorted_idx,
                         const unsigned* __restrict__ row_end,
                         const unsigned* __restrict__ uniq_cc,
                         const unsigned* __restrict__ nuq_p,
                         f4* __restrict__ outF4,
                         f4* __restrict__ outC4, int n) {
    int tid = blockIdx.x * 256 + threadIdx.x;
    int wave = tid >> 6;
    int lane = threadIdx.x & 63;
    int q = lane >> 4;
    int sub = lane & 15;
    int rb = wave * 16 + q;
    int nuq = (int)*nuq_p;

    if (rb + 12 < nuq) {   // fast path: all 4 rows valid
        int r[4];
        unsigned en[4], cc[4];
#pragma unroll
        for (int k = 0; k < 4; ++k) r[k] = rb + k * 4;
#pragma unroll
        for (int k = 0; k < 4; ++k) en[k] = row_end[r[k]];
#pragma unroll
        for (int k = 0; k < 4; ++k) cc[k] = uniq_cc[r[k]];
        int cnt[4], st[4], i0[4];
#pragma unroll
        for (int k = 0; k < 4; ++k) {
            cnt[k] = (int)(cc[k] >> 22);
            st[k] = (int)en[k] - cnt[k];
        }
#pragma unroll
        for (int k = 0; k < 4; ++k) i0[k] = sorted_idx[st[k]];
        f4 a[4];
#pragma unroll
        for (int k = 0; k < 4; ++k)
            a[k] = feats4[(size_t)i0[k] * 16 + sub];
#pragma unroll
        for (int k = 0; k < 4; ++k) {
            if (cnt[k] > 1) {
                for (int m = 1; m < cnt[k]; ++m) {
                    int i = sorted_idx[st[k] + m];
                    a[k] += feats4[(size_t)i * 16 + sub];
                }
                a[k] *= (1.0f / (float)cnt[k]);
            }
            outF4[(size_t)r[k] * 16 + sub] = a[k];
            if (sub == 0) {
                unsigned code = cc[k] & 0x3FFFFFu;
                f4 cv = {(float)(code >> 21), (float)((code >> 14) & 127),
                         (float)((code >> 7) & 127), (float)(code & 127)};
                outC4[r[k]] = cv;
            }
        }
    } else {
#pragma unroll
        for (int k = 0; k < 4; ++k) {
            int r = rb + k * 4;
            if (r >= n) continue;
            if (r < nuq) {
                unsigned en = row_end[r];
                unsigned cc = uniq_cc[r];
                int cnt = (int)(cc >> 22);
                int st = (int)en - cnt;
                f4 a = {0.f, 0.f, 0.f, 0.f};
                for (int m = 0; m < cnt; ++m) {
                    int i = sorted_idx[st + m];
                    a += feats4[(size_t)i * 16 + sub];
                }
                a *= (1.0f / (float)cnt);
                outF4[(size_t)r * 16 + sub] = a;
                if (sub == 0) {
                    unsigned code = cc & 0x3FFFFFu;
                    f4 cv = {(float)(code >> 21), (float)((code >> 14) & 127),
                             (float)((code >> 7) & 127), (float)(code & 127)};
                    outC4[r] = cv;
                }
            } else {
                f4 zz = {0.f, 0.f, 0.f, 0.f};
                outF4[(size_t)r * 16 + sub] = zz;
                if (sub == 0) {
                    f4 mm = {-1.f, -1.f, -1.f, -1.f};
                    outC4[r] = mm;
                }
            }
        }
    }
}

extern "C" void kernel_launch(void* const* d_in, const int* in_sizes, int n_in,
                              void* d_out, int out_size, void* d_ws, size_t ws_size,
                              hipStream_t stream) {
    const float* feats = (const float*)d_in[0];
    const int* coords = (const int*)d_in[1];
    const int n = in_sizes[1] / 4;   // N = 500000

    float* outF = (float*)d_out;
    f4* outC4 = (f4*)(outF + (size_t)n * 64);

    unsigned* cnt8 = (unsigned*)d_ws;              // NW u32 (4.19 MB), 16-al
    u64* btot = (u64*)(cnt8 + NW);                 // 4096 u64
    unsigned* nuq = (unsigned*)(btot + HBLK);      // 1 (+1 pad)
    int* codes = (int*)(nuq + 2);                  // n
    unsigned* wprefix = (unsigned*)(codes + n);    // NW u32 (4.19 MB)
    unsigned* uniq_cc = wprefix + NW;              // n
    unsigned* row_end = uniq_cc + n;               // n
    int* sorted_idx = (int*)(row_end + n);         // n

    zero_cnt<<<1024, 256, 0, stream>>>((uint4*)cnt8);
    count_codes<<<(n + 255) / 256, 256, 0, stream>>>(coords, cnt8, codes, n);
    block_sums<<<HBLK, 256, 0, stream>>>(cnt8, btot);
    scan_totals<<<1, 1024, 0, stream>>>(btot, nuq);
    scan_write<<<HBLK, 256, 0, stream>>>(cnt8, btot, wprefix, uniq_cc, row_end);
    fill_sorted<<<(n + 255) / 256, 256, 0, stream>>>(codes, cnt8, wprefix, row_end, sorted_idx, n);

    int waves = (n + 15) / 16;
    int blocks = (waves * 64 + 255) / 256;
    gather16<<<blocks, 256, 0, stream>>>((const f4*)feats, sorted_idx,
                                         row_end, uniq_cc, nuq,
                                         (f4*)outF, outC4, n);
}

// Round 17
// 117.814 us; speedup vs baseline: 8.1659x; 1.0444x over previous
//
#include <hip/hip_runtime.h>

// Sparse voxel downsample (FACTOR=2, RES=256 -> res=128, B=2, C=64).
// code = ((b*128 + x/2)*128 + y/2)*128 + z/2  in [0, 4194304)
// u8 dense histogram + 2-level packed (flag,count) scan -> sorted rank AND
// row_start per unique code (== jnp.unique order). Rank re-derived from
// per-word occupied-prefix (wprefix). Counting-sort the INDICES by rank,
// then a gather hot pass (depth 4 = fastest measured): sequential NT writes,
// random 256B regular reads (L3-warm feats), in-register mean, no atomics.
// [Best measured configuration: 118.0 us. Hot pass pinned at ~1.6 TB/s
// random-256B side across 7 structural variants; preamble fusion via
// grid.sync (575us) and decoupled lookback (890us) both measured far worse
// than 6 small launches (~35us) -- cross-XCD coordination dominates.]

#define RES2 128
#define NCODES (2 * 128 * 128 * 128)   // 4194304 codes
#define NW (NCODES / 4)                // u32 words in u8 histogram
#define HBLK 4096                      // blocks over code space (1024 codes)

typedef unsigned long long u64;
typedef float f4 __attribute__((ext_vector_type(4)));

// Zero cnt8 (4.19 MB) with uint4 stores (runtime fill kernel runs at 53 GB/s).
__global__ void zero_cnt(uint4* __restrict__ p) {
    int i = blockIdx.x * 256 + threadIdx.x;   // 1024*256 = 262144 = NW/4
    p[i] = make_uint4(0u, 0u, 0u, 0u);
}

__global__ void count_codes(const int* __restrict__ coords,
                            unsigned* __restrict__ cnt8,
                            int* __restrict__ codes, int n) {
    int i = blockIdx.x * 256 + threadIdx.x;
    if (i >= n) return;
    const int4 v = reinterpret_cast<const int4*>(coords)[i];
    int code = (((v.x * RES2 + (v.y >> 1)) * RES2 + (v.z >> 1)) * RES2) + (v.w >> 1);
    codes[i] = code;
    atomicAdd(&cnt8[code >> 2], 1u << (8 * (code & 3)));   // u8 lanes, max ~9
}

// Per block of 1024 codes: packed (count_sum<<32 | flag_sum).
__global__ void block_sums(const unsigned* __restrict__ cnt8,
                           u64* __restrict__ btot) {
    __shared__ u64 sh[256];
    int t = threadIdx.x;
    unsigned w = cnt8[blockIdx.x * 256 + t];
    unsigned c0 = w & 0xFFu, c1 = (w >> 8) & 0xFFu,
             c2 = (w >> 16) & 0xFFu, c3 = w >> 24;
    u64 s = ((u64)(c0 + c1 + c2 + c3) << 32) |
            (u64)((c0 != 0) + (c1 != 0) + (c2 != 0) + (c3 != 0));
    sh[t] = s;
    __syncthreads();
    for (int off = 128; off > 0; off >>= 1) {
        if (t < off) sh[t] += sh[t + off];
        __syncthreads();
    }
    if (t == 0) btot[blockIdx.x] = sh[0];
}

// Single block: exclusive scan over 4096 packed totals; n_unique -> *nuq.
__global__ void scan_totals(u64* __restrict__ btot, unsigned* __restrict__ nuq) {
    __shared__ u64 sh[1024];
    int t = threadIdx.x;
    int base = t * 4;
    u64 v[4], e[4], s = 0;
#pragma unroll
    for (int j = 0; j < 4; ++j) { v[j] = btot[base + j]; e[j] = s; s += v[j]; }
    sh[t] = s;
    __syncthreads();
    for (int off = 1; off < 1024; off <<= 1) {
        u64 add = (t >= off) ? sh[t - off] : 0ull;
        __syncthreads();
        sh[t] += add;
        __syncthreads();
    }
    u64 excl = (t == 0) ? 0ull : sh[t - 1];
#pragma unroll
    for (int j = 0; j < 4; ++j) btot[base + j] = excl + e[j];
    if (t == 1023) *nuq = (unsigned)(sh[1023] & 0xFFFFFFFFull);
}

// Second pass: per-block packed scan + base. wprefix[word] = flag prefix
// (sequential write); per occupied code (r monotone -> near-sequential):
// uniq_cc[r] = code | cnt<<22;  row_end[r] = row_start.
__global__ void scan_write(const unsigned* __restrict__ cnt8,
                           const u64* __restrict__ btot,
                           unsigned* __restrict__ wprefix,
                           unsigned* __restrict__ uniq_cc,
                           unsigned* __restrict__ row_end) {
    __shared__ u64 sh[256];
    int t = threadIdx.x;
    int widx = blockIdx.x * 256 + t;
    unsigned w = cnt8[widx];
    unsigned c4[4] = {w & 0xFFu, (w >> 8) & 0xFFu, (w >> 16) & 0xFFu, w >> 24};
    u64 e[4], s = 0;
#pragma unroll
    for (int j = 0; j < 4; ++j) {
        e[j] = s;
        s += ((u64)c4[j] << 32) | (u64)(c4[j] != 0);
    }
    sh[t] = s;
    __syncthreads();
    for (int off = 1; off < 256; off <<= 1) {
        u64 add = (t >= off) ? sh[t - off] : 0ull;
        __syncthreads();
        sh[t] += add;
        __syncthreads();
    }
    u64 texcl = ((t == 0) ? 0ull : sh[t - 1]) + btot[blockIdx.x];
    wprefix[widx] = (unsigned)(texcl & 0xFFFFFFFFull);
    int cbase = widx * 4;
#pragma unroll
    for (int j = 0; j < 4; ++j) {
        if (c4[j]) {
            unsigned r = (unsigned)((texcl + e[j]) & 0xFFFFFFFFull);
            unsigned st = (unsigned)((texcl + e[j]) >> 32);
            int code = cbase + j;
            uniq_cc[r] = (unsigned)code | (c4[j] << 22);
            row_end[r] = st;
        }
    }
}

// Counting sort of indices by rank (rank recomputed from cnt8 + wprefix).
// After this, row_end[r] = start+cnt.
__global__ void fill_sorted(const int* __restrict__ codes,
                            const unsigned* __restrict__ cnt8,
                            const unsigned* __restrict__ wprefix,
                            unsigned* __restrict__ row_end,
                            int* __restrict__ sorted_idx, int n) {
    int i = blockIdx.x * 256 + threadIdx.x;
    if (i >= n) return;
    int c = codes[i];
    unsigned w = cnt8[c >> 2];
    unsigned base = wprefix[c >> 2];
    int j = c & 3;
    unsigned occ = 0;
    if (j > 0) occ += ((w & 0xFFu) != 0);
    if (j > 1) occ += (((w >> 8) & 0xFFu) != 0);
    if (j > 2) occ += (((w >> 16) & 0xFFu) != 0);
    unsigned r = base + occ;
    unsigned pos = atomicAdd(&row_end[r], 1u);
    sorted_idx[pos] = i;
}

// Hot pass: 16 output rows per wave (quarter-wave = one 256B row, 4 batches
// = measured-optimal MLP depth). Regular loads (L3-warm feats), NT stores.
__global__ void gather16(const f4* __restrict__ feats4,
                         const int* __restrict__ sorted_idx,
                         const unsigned* __restrict__ row_end,
                         const unsigned* __restrict__ uniq_cc,
                         const unsigned* __restrict__ nuq_p,
                         f4* __restrict__ outF4,
                         f4* __restrict__ outC4, int n) {
    int tid = blockIdx.x * 256 + threadIdx.x;
    int wave = tid >> 6;
    int lane = threadIdx.x & 63;
    int q = lane >> 4;
    int sub = lane & 15;
    int rb = wave * 16 + q;
    int nuq = (int)*nuq_p;

    if (rb + 12 < nuq) {   // fast path: all 4 rows valid
        int r[4];
        unsigned en[4], cc[4];
#pragma unroll
        for (int k = 0; k < 4; ++k) r[k] = rb + k * 4;
#pragma unroll
        for (int k = 0; k < 4; ++k) en[k] = row_end[r[k]];
#pragma unroll
        for (int k = 0; k < 4; ++k) cc[k] = uniq_cc[r[k]];
        int cnt[4], st[4], i0[4];
#pragma unroll
        for (int k = 0; k < 4; ++k) {
            cnt[k] = (int)(cc[k] >> 22);
            st[k] = (int)en[k] - cnt[k];
        }
#pragma unroll
        for (int k = 0; k < 4; ++k) i0[k] = sorted_idx[st[k]];
        f4 a[4];
#pragma unroll
        for (int k = 0; k < 4; ++k)
            a[k] = feats4[(size_t)i0[k] * 16 + sub];
#pragma unroll
        for (int k = 0; k < 4; ++k) {
            if (cnt[k] > 1) {
                for (int m = 1; m < cnt[k]; ++m) {
                    int i = sorted_idx[st[k] + m];
                    a[k] += feats4[(size_t)i * 16 + sub];
                }
                a[k] *= (1.0f / (float)cnt[k]);
            }
            __builtin_nontemporal_store(a[k], &outF4[(size_t)r[k] * 16 + sub]);
            if (sub == 0) {
                unsigned code = cc[k] & 0x3FFFFFu;
                f4 cv = {(float)(code >> 21), (float)((code >> 14) & 127),
                         (float)((code >> 7) & 127), (float)(code & 127)};
                __builtin_nontemporal_store(cv, &outC4[r[k]]);
            }
        }
    } else {
#pragma unroll
        for (int k = 0; k < 4; ++k) {
            int r = rb + k * 4;
            if (r >= n) continue;
            if (r < nuq) {
                unsigned en = row_end[r];
                unsigned cc = uniq_cc[r];
                int cnt = (int)(cc >> 22);
                int st = (int)en - cnt;
                f4 a = {0.f, 0.f, 0.f, 0.f};
                for (int m = 0; m < cnt; ++m) {
                    int i = sorted_idx[st + m];
                    a += feats4[(size_t)i * 16 + sub];
                }
                a *= (1.0f / (float)cnt);
                outF4[(size_t)r * 16 + sub] = a;
                if (sub == 0) {
                    unsigned code = cc & 0x3FFFFFu;
                    f4 cv = {(float)(code >> 21), (float)((code >> 14) & 127),
                             (float)((code >> 7) & 127), (float)(code & 127)};
                    outC4[r] = cv;
                }
            } else {
                f4 zz = {0.f, 0.f, 0.f, 0.f};
                outF4[(size_t)r * 16 + sub] = zz;
                if (sub == 0) {
                    f4 mm = {-1.f, -1.f, -1.f, -1.f};
                    outC4[r] = mm;
                }
            }
        }
    }
}

extern "C" void kernel_launch(void* const* d_in, const int* in_sizes, int n_in,
                              void* d_out, int out_size, void* d_ws, size_t ws_size,
                              hipStream_t stream) {
    const float* feats = (const float*)d_in[0];
    const int* coords = (const int*)d_in[1];
    const int n = in_sizes[1] / 4;   // N = 500000

    float* outF = (float*)d_out;
    f4* outC4 = (f4*)(outF + (size_t)n * 64);

    unsigned* cnt8 = (unsigned*)d_ws;              // NW u32 (4.19 MB), 16-al
    u64* btot = (u64*)(cnt8 + NW);                 // 4096 u64
    unsigned* nuq = (unsigned*)(btot + HBLK);      // 1 (+1 pad)
    int* codes = (int*)(nuq + 2);                  // n
    unsigned* wprefix = (unsigned*)(codes + n);    // NW u32 (4.19 MB)
    unsigned* uniq_cc = wprefix + NW;              // n
    unsigned* row_end = uniq_cc + n;               // n
    int* sorted_idx = (int*)(row_end + n);         // n

    zero_cnt<<<1024, 256, 0, stream>>>((uint4*)cnt8);
    count_codes<<<(n + 255) / 256, 256, 0, stream>>>(coords, cnt8, codes, n);
    block_sums<<<HBLK, 256, 0, stream>>>(cnt8, btot);
    scan_totals<<<1, 1024, 0, stream>>>(btot, nuq);
    scan_write<<<HBLK, 256, 0, stream>>>(cnt8, btot, wprefix, uniq_cc, row_end);
    fill_sorted<<<(n + 255) / 256, 256, 0, stream>>>(codes, cnt8, wprefix, row_end, sorted_idx, n);

    int waves = (n + 15) / 16;
    int blocks = (waves * 64 + 255) / 256;
    gather16<<<blocks, 256, 0, stream>>>((const f4*)feats, sorted_idx,
                                         row_end, uniq_cc, nuq,
                                         (f4*)outF, outC4, n);
}